// Round 6
// baseline (482.173 us; speedup 1.0000x reference)
//
#include <hip/hip_runtime.h>

typedef __attribute__((ext_vector_type(4)))  float f32x4;
typedef __attribute__((ext_vector_type(16))) float f32x16;
typedef __attribute__((ext_vector_type(8)))  short s16x8;

// ---------------- output layout (float element offsets) ----------------
#define OFF1_OFF 0
#define OFF2_OFF 4718592
#define OFF3_OFF 5898240
#define R11_OFF  6193152      // 4*64*256*256 f32
#define R21_OFF  22970368     // 4*128*128*128 f32 (n1b+n2b scratch pre-VGG)
#define R31_OFF  31358976     // 4*256*64*64 f32

__device__ __forceinline__ ushort f2bf(float x) {
  union { float f; uint u; } c; c.f = x;
  uint r = c.u + 0x7FFFu + ((c.u >> 16) & 1u);
  return (ushort)(r >> 16);
}
__device__ __forceinline__ float bfval(ushort h) {
  union { uint u; float f; } c; c.u = ((uint)h) << 16;
  return c.f;
}

// ---------------- per-pixel channel L2 normalize -> bf16 hi/lo pos-major
// out per sample: [pos 4096][cc 8][hi 32 | lo 32] ushort (512/pos).
__global__ __launch_bounds__(256)
void k_normalize(const float* __restrict__ f1, const float* __restrict__ f2,
                 ushort* __restrict__ n1b, ushort* __restrict__ n2b) {
  __shared__ uint ldsu[64 * 256];
  float* red = (float*)ldsu;
  float* inv = (float*)ldsu + 256;
  const int t = threadIdx.x, x = t & 63, cg = t >> 6;
  const int h = blockIdx.x, b = blockIdx.y;
  const float* in = blockIdx.z ? f2 : f1;
  ushort* op = blockIdx.z ? n2b : n1b;
  const size_t base = (size_t)b * 256 * 4096 + (size_t)h * 64 + x;
  float vals[64];
  float s = 0.f;
  #pragma unroll
  for (int ci = 0; ci < 64; ++ci) {
    float v = in[base + (size_t)(cg * 64 + ci) * 4096];
    vals[ci] = v;
    s = fmaf(v, v, s);
  }
  red[t] = s;
  __syncthreads();
  if (t < 64) {
    float tot = red[t] + red[64 + t] + red[128 + t] + red[192 + t];
    inv[t] = 1.0f / fmaxf(sqrtf(tot), 1e-12f);
  }
  __syncthreads();
  const float iv = inv[x];
  __syncthreads();
  #pragma unroll
  for (int j = 0; j < 32; ++j) {
    float v0 = vals[2 * j] * iv, v1 = vals[2 * j + 1] * iv;
    ushort h0 = f2bf(v0), h1 = f2bf(v1);
    ushort l0 = f2bf(v0 - bfval(h0)), l1 = f2bf(v1 - bfval(h1));
    int cc = (cg << 1) + (j >> 4);
    int i = j & 15;
    int qh = cc * 32 + i, ql = cc * 32 + 16 + i;
    ldsu[x * 256 + (qh ^ (x & 31))] = (uint)h0 | ((uint)h1 << 16);
    ldsu[x * 256 + (ql ^ (x & 31))] = (uint)l0 | ((uint)l1 << 16);
  }
  __syncthreads();
  uint* og = (uint*)(op + ((size_t)b * 4096 + h * 64) * 512);
  #pragma unroll
  for (int it = 0; it < 64; ++it) {
    int idx = it * 256 + t;
    int p = idx >> 8, q = idx & 255;
    og[idx] = ldsu[p * 256 + (q ^ (p & 31))];
  }
}

// ---------------- pixel-correlation GEMM v3 (MFMA 32x32x16 bf16x3) ----
// batched z=4; P written PLANE-MAJOR: P[(uy*64+vy)*4096 + ux*64 + vx].
// T3+T4: dbuf LDS via global_load_lds (linear dest, pre-swizzled src),
// counted vmcnt(8) across barriers; vmcnt(0) only on the last chunk.
__global__ __launch_bounds__(256)
void k_pgemm_mfma(const ushort* __restrict__ Ab0, const ushort* __restrict__ Bb0,
                  float* __restrict__ P0) {
  __shared__ __align__(16) ushort AsB[2][8192];
  __shared__ __align__(16) ushort BsB[2][8192];
  const int t = threadIdx.x;
  const int bz = blockIdx.z;
  const ushort* Ab = Ab0 + (size_t)bz * 2097152 + (size_t)blockIdx.y * 128 * 512;
  const ushort* Bb = Bb0 + (size_t)bz * 2097152 + (size_t)blockIdx.x * 128 * 512;
  float* P = P0 + (size_t)bz * 16777216;
  const int lane = t & 63, wv = t >> 6;
  const int wm = wv >> 1, wn = wv & 1;
  const int l31 = lane & 31, lh = lane >> 5;

// linear LDS dest unit u = (wv*4+j)*64 + lane; row=u>>3, lds slot=u&7;
// global slot = (u&7) ^ (row&7)  (same involution the reads use)
#define STAGE(buf, cc)                                                         \
  do {                                                                         \
    _Pragma("unroll")                                                          \
    for (int j = 0; j < 4; ++j) {                                              \
      int u = (wv * 4 + j) * 64 + lane;                                        \
      int row = u >> 3;                                                        \
      int gs = (u & 7) ^ (row & 7);                                            \
      __builtin_amdgcn_global_load_lds(                                        \
          (const __attribute__((address_space(1))) void*)(Ab + (size_t)row * 512 + (cc) * 64 + gs * 8), \
          (__attribute__((address_space(3))) void*)(AsB[buf] + u * 8), 16, 0, 0); \
      __builtin_amdgcn_global_load_lds(                                        \
          (const __attribute__((address_space(1))) void*)(Bb + (size_t)row * 512 + (cc) * 64 + gs * 8), \
          (__attribute__((address_space(3))) void*)(BsB[buf] + u * 8), 16, 0, 0); \
    }                                                                          \
  } while (0)

  f32x16 acc[2][2];
  #pragma unroll
  for (int mt = 0; mt < 2; ++mt)
    #pragma unroll
    for (int nt = 0; nt < 2; ++nt)
      #pragma unroll
      for (int r = 0; r < 16; ++r) acc[mt][nt][r] = 0.f;

  STAGE(0, 0);
  STAGE(1, 1);

  #pragma unroll 1
  for (int cc = 0; cc < 8; ++cc) {
    const int cur = cc & 1;
    if (cc < 7) { asm volatile("s_waitcnt vmcnt(8)" ::: "memory"); }
    else        { asm volatile("s_waitcnt vmcnt(0)" ::: "memory"); }
    __builtin_amdgcn_s_barrier();
    __builtin_amdgcn_sched_barrier(0);
    const ushort* As = AsB[cur];
    const ushort* Bs = BsB[cur];
    s16x8 ah[2][2], al[2][2], bh[2][2], bl[2][2];
    #pragma unroll
    for (int mt = 0; mt < 2; ++mt) {
      const int row = wm * 64 + mt * 32 + l31;
      const int rx = row & 7;
      const ushort* pr = As + (row << 6);
      ah[mt][0] = *(const s16x8*)(pr + ((0 + lh) ^ rx) * 8);
      ah[mt][1] = *(const s16x8*)(pr + ((2 + lh) ^ rx) * 8);
      al[mt][0] = *(const s16x8*)(pr + ((4 + lh) ^ rx) * 8);
      al[mt][1] = *(const s16x8*)(pr + ((6 + lh) ^ rx) * 8);
    }
    #pragma unroll
    for (int nt = 0; nt < 2; ++nt) {
      const int row = wn * 64 + nt * 32 + l31;
      const int rx = row & 7;
      const ushort* pr = Bs + (row << 6);
      bh[nt][0] = *(const s16x8*)(pr + ((0 + lh) ^ rx) * 8);
      bh[nt][1] = *(const s16x8*)(pr + ((2 + lh) ^ rx) * 8);
      bl[nt][0] = *(const s16x8*)(pr + ((4 + lh) ^ rx) * 8);
      bl[nt][1] = *(const s16x8*)(pr + ((6 + lh) ^ rx) * 8);
    }
    #pragma unroll
    for (int mt = 0; mt < 2; ++mt)
      #pragma unroll
      for (int nt = 0; nt < 2; ++nt) {
        acc[mt][nt] = __builtin_amdgcn_mfma_f32_32x32x16_bf16(al[mt][0], bh[nt][0], acc[mt][nt], 0, 0, 0);
        acc[mt][nt] = __builtin_amdgcn_mfma_f32_32x32x16_bf16(al[mt][1], bh[nt][1], acc[mt][nt], 0, 0, 0);
        acc[mt][nt] = __builtin_amdgcn_mfma_f32_32x32x16_bf16(ah[mt][0], bl[nt][0], acc[mt][nt], 0, 0, 0);
        acc[mt][nt] = __builtin_amdgcn_mfma_f32_32x32x16_bf16(ah[mt][1], bl[nt][1], acc[mt][nt], 0, 0, 0);
        acc[mt][nt] = __builtin_amdgcn_mfma_f32_32x32x16_bf16(ah[mt][0], bh[nt][0], acc[mt][nt], 0, 0, 0);
        acc[mt][nt] = __builtin_amdgcn_mfma_f32_32x32x16_bf16(ah[mt][1], bh[nt][1], acc[mt][nt], 0, 0, 0);
      }
    __builtin_amdgcn_sched_barrier(0);
    __builtin_amdgcn_s_barrier();
    if (cc < 6) STAGE(cur, cc + 2);
  }
#undef STAGE

  // plane-major epilogue: wave owns one 64x64 plane; 32x32 C/D layout:
  // col = lane&31, row = (reg&3) + 8*(reg>>2) + 4*(lane>>5)
  const int plane = ((blockIdx.y * 2 + wm) << 6) + blockIdx.x * 2 + wn;
  float* Pp = P + (size_t)plane * 4096;
  #pragma unroll
  for (int mt = 0; mt < 2; ++mt)
    #pragma unroll
    for (int nt = 0; nt < 2; ++nt)
      #pragma unroll
      for (int r = 0; r < 16; ++r) {
        const int rowf = (r & 3) + 8 * (r >> 2) + 4 * lh;
        Pp[(mt * 32 + rowf) * 64 + nt * 32 + l31] = acc[mt][nt][r];
      }
}

// ---------------- corr v2: separable 9-tap + partial argmax ----------
__global__ __launch_bounds__(256)
void k_corr(const float* __restrict__ P0, float* __restrict__ pv0,
            int* __restrict__ pi0) {
  __shared__ __align__(16) f32x4 Pl[3 * 1024];
  __shared__ float rv[256];
  __shared__ int   ri[256];
  const int t = threadIdx.x;
  const int orig = blockIdx.x;
  const int w = (orig & 7) * 1922 + (orig >> 3);
  const int bz = w / 3844;
  const int r2 = w % 3844;
  const int py = r2 / 62, qy = r2 % 62;
  const float* P = P0 + (size_t)bz * 16777216;
  float* pv = pv0 + (size_t)bz * 238328;
  int*   pi = pi0 + (size_t)bz * 238328;
  #pragma unroll
  for (int i = 0; i < 12; ++i) {
    int e = t + i * 256;
    int blk = e >> 10, rem = e & 1023;
    int px = rem >> 4, q4 = rem & 15;
    int pidx = (py + blk) * 64 + (qy + blk);
    f32x4 v = *(const f32x4*)(P + (size_t)pidx * 4096 + rem * 4);
    int slot = ((q4 + (px >> 4)) & 15) ^ (px & 15);
    Pl[blk * 1024 + px * 16 + slot] = v;
  }
  __syncthreads();
  const int px = t & 63, cg = t >> 6;
  #pragma unroll
  for (int j = 0; j < 4; ++j) {
    int c = cg * 4 + j;
    int slot = ((c + (px >> 4)) & 15) ^ (px & 15);
    int o = px * 16 + slot;
    Pl[o] = Pl[o] + Pl[1024 + o] + Pl[2048 + o];
  }
  __syncthreads();
  float bv = -3.4e38f; int bq = 0;
  if (px < 62) {
    const int q0 = cg * 16;
    const int nq = (cg < 3) ? 16 : 14;
    const int nch = (cg < 3) ? 5 : 4;
    float f[3][20];
    #pragma unroll
    for (int dj = 0; dj < 3; ++dj) {
      const int row = px + dj;
      const int rr = row >> 4, rm = row & 15;
      #pragma unroll
      for (int cc2 = 0; cc2 < 5; ++cc2) {
        if (cc2 < nch) {
          int c = cg * 4 + cc2;
          int slot = ((c + rr) & 15) ^ rm;
          f32x4 v = Pl[row * 16 + slot];
          f[dj][cc2 * 4 + 0] = v[0];
          f[dj][cc2 * 4 + 1] = v[1];
          f[dj][cc2 * 4 + 2] = v[2];
          f[dj][cc2 * 4 + 3] = v[3];
        }
      }
    }
    #pragma unroll
    for (int l = 0; l < 16; ++l) {
      if (l < nq) {
        float s = f[0][l] + f[1][l + 1] + f[2][l + 2];
        if (s > bv) { bv = s; bq = q0 + l; }
      }
    }
  }
  rv[t] = bv; ri[t] = bq;
  __syncthreads();
  if (t < 62) {
    float v = rv[t]; int q = ri[t];
    #pragma unroll
    for (int g = 1; g < 4; ++g) {
      float v2 = rv[g * 64 + t];
      if (v2 > v) { v = v2; q = ri[g * 64 + t]; }
    }
    const int n = py * 62 + t;
    pv[(size_t)n * 62 + qy] = v;
    pi[(size_t)n * 62 + qy] = qy * 62 + q;
  }
}

// ---------------- final argmax over the 62 qy partials ---------------
__global__ void k_argmax(const float* __restrict__ pv, const int* __restrict__ pi,
                         int* __restrict__ idxf) {
  int tid = blockIdx.x * 256 + threadIdx.x;
  if (tid >= 4 * 3844) return;
  const float* v = pv + (size_t)tid * 62;
  const int*  ii = pi + (size_t)tid * 62;
  float bv = v[0]; int bi = ii[0];
  for (int q = 1; q < 62; ++q) {
    float x = v[q];
    if (x > bv) { bv = x; bi = ii[q]; }
  }
  idxf[tid] = bi;
}

// ---------------- flow pyramid + 9 shifts (all 3 levels merged) ------
__global__ void k_flow_all(const int* __restrict__ idxf, float* __restrict__ out) {
  int gid = blockIdx.x * 256 + threadIdx.x;
  int Ho, lg, rel = gid;
  float* o;
  if (gid < 2359296)      { Ho = 256; lg = 2; o = out + OFF1_OFF; }
  else if (gid < 2949120) { Ho = 128; lg = 1; o = out + OFF2_OFF; rel -= 2359296; }
  else if (gid < 3096576) { Ho = 64;  lg = 0; o = out + OFF3_OFF; rel -= 2949120; }
  else return;
  const int x = rel % Ho;
  const int y = (rel / Ho) % Ho;
  const int s = (rel / (Ho * Ho)) % 9;
  const int b = rel / (Ho * Ho * 9);
  const int i = s / 3, j = s % 3;
  const int sc = 1 << lg;
  const int yy = y - i * sc, xx = x - j * sc;
  float fw = 0.f, fh = 0.f;
  if (yy >= 0 && xx >= 0) {
    const int r = yy >> lg, c = xx >> lg;
    if (r < 62 && c < 62) {
      const int id = idxf[b * 3844 + r * 62 + c];
      fw = (float)((id % 62 - c) * sc);
      fh = (float)((id / 62 - r) * sc);
    }
  }
  float2 ov = {fw, fh};
  *(float2*)(o + (size_t)rel * 2) = ov;
}

// ---------------- weight prep: f32 OIHW -> bf16 [oc][tap][ci] --------
__global__ void k_wprep_all(const float* __restrict__ w12, const float* __restrict__ w21,
                            const float* __restrict__ w22, const float* __restrict__ w31,
                            ushort* __restrict__ o12, ushort* __restrict__ o21,
                            ushort* __restrict__ o22, ushort* __restrict__ o31) {
  int gid = blockIdx.x * 256 + threadIdx.x;
  const float* w; ushort* o; int CIN, rel;
  if (gid < 36864)        { w = w12; o = o12; CIN = 64;  rel = gid; }
  else if (gid < 110592)  { w = w21; o = o21; CIN = 64;  rel = gid - 36864; }
  else if (gid < 258048)  { w = w22; o = o22; CIN = 128; rel = gid - 110592; }
  else if (gid < 552960)  { w = w31; o = o31; CIN = 128; rel = gid - 258048; }
  else return;
  int ci = rel % CIN;
  int r = rel / CIN;
  int tap = r % 9;
  int oc = r / 9;
  o[((size_t)oc * 9 + tap) * CIN + ci] = f2bf(w[((size_t)oc * CIN + ci) * 9 + tap]);
}

// ---------------- conv1_1 (batched y): 3->64, fused input norm --------
__global__ __launch_bounds__(256)
void k_conv11(const float* __restrict__ img0, const float* __restrict__ w,
              const float* __restrict__ bias, float* __restrict__ outF0,
              ushort* __restrict__ outB0) {
  __shared__ float wl[1728];
  __shared__ float bl[64];
  const int t = threadIdx.x;
  const int b = blockIdx.y;
  const float* img = img0 + (size_t)b * 3 * 65536;
  float* outF = outF0 + (size_t)b * 64 * 65536;
  ushort* outB = outB0 + (size_t)b * 4194304;
  for (int i = t; i < 1728; i += 256) wl[i] = w[i];
  if (t < 64) bl[t] = bias[t];
  __syncthreads();
  const int x = t, y = blockIdx.x;
  const float mean[3] = {0.485f, 0.456f, 0.406f};
  const float stdv[3] = {0.229f, 0.224f, 0.225f};
  float v[27];
  #pragma unroll
  for (int c = 0; c < 3; ++c)
    #pragma unroll
    for (int dy = 0; dy < 3; ++dy)
      #pragma unroll
      for (int dx = 0; dx < 3; ++dx) {
        int iy = y + dy - 1, ix = x + dx - 1;
        float val = 0.f;
        if (iy >= 0 && iy < 256 && ix >= 0 && ix < 256)
          val = (img[((size_t)c * 256 + iy) * 256 + ix] - mean[c]) / stdv[c];
        v[c * 9 + dy * 3 + dx] = val;
      }
  float ov[64];
  #pragma unroll 4
  for (int oc = 0; oc < 64; ++oc) {
    float a = bl[oc];
    #pragma unroll
    for (int k = 0; k < 27; ++k) a = fmaf(wl[oc * 27 + k], v[k], a);
    a = fmaxf(a, 0.f);
    ov[oc] = a;
    outF[((size_t)oc * 256 + y) * 256 + x] = a;
  }
  uint* ob = (uint*)(outB + ((((size_t)y) * 256 + x) << 6));
  #pragma unroll
  for (int j = 0; j < 32; ++j)
    ob[j] = (uint)f2bf(ov[2 * j]) | ((uint)f2bf(ov[2 * j + 1]) << 16);
}

// ---------------- MFMA 3x3 conv, single-pass bf16, batched z ----------
template <int CIN, bool POOL, bool WB16>
__global__ __launch_bounds__(256)
void k_mconv(const ushort* __restrict__ inb, const ushort* __restrict__ wB,
             const float* __restrict__ bias, float* __restrict__ outF,
             ushort* __restrict__ outB, int H, int W, int Cout,
             int inStride, int fStride, int bStride) {
  __shared__ __align__(16) char lds_raw[33792];
  ushort* As = (ushort*)lds_raw;
  float*  sm = (float*)lds_raw;
  const int t = threadIdx.x;
  const int bz = blockIdx.z;
  inb += (size_t)bz * inStride;
  outF += (size_t)bz * fStride;
  outB += (size_t)bz * bStride;
  const int xtiles = W >> 6;
  const int xt = blockIdx.x % xtiles;
  const int yp = blockIdx.x / xtiles;
  const int x0 = xt << 6, y0 = yp << 1;
  const int ocb = blockIdx.y << 6;
  const int lane = t & 63, wv = t >> 6;
  const int wm = wv >> 1, wn = wv & 1;
  const int lr = lane & 15, lk = lane >> 4;
  constexpr int NC2 = CIN / 64;

  f32x4 acc[4][2];
  #pragma unroll
  for (int mr = 0; mr < 4; ++mr)
    #pragma unroll
    for (int n = 0; n < 2; ++n) {
      f32x4 z = {0.f, 0.f, 0.f, 0.f};
      acc[mr][n] = z;
    }

  #pragma unroll 1
  for (int cc = 0; cc < NC2; ++cc) {
    __syncthreads();
    #pragma unroll
    for (int i = 0; i < 9; ++i) {
      int e = t + i * 256;
      if (e < 2112) {
        int pos = e >> 3, cig = e & 7;
        int hy = pos / 66, hx = pos - hy * 66;
        int gy = y0 + hy - 1, gx = x0 + hx - 1;
        s16x8 v = {0, 0, 0, 0, 0, 0, 0, 0};
        if (gy >= 0 && gy < H && gx >= 0 && gx < W)
          v = *(const s16x8*)(inb + ((size_t)gy * W + gx) * CIN + cc * 64 + cig * 8);
        *(s16x8*)(As + ((pos << 3) + (cig ^ (pos & 7))) * 8) = v;
      }
    }
    __syncthreads();
    #pragma unroll 3
    for (int tap = 0; tap < 9; ++tap) {
      const int dy = tap / 3, dx = tap % 3;
      s16x8 b0[2], b1[2];
      #pragma unroll
      for (int n = 0; n < 2; ++n) {
        const ushort* wp =
            wB + ((size_t)(ocb + wn * 32 + n * 16 + lr) * 9 + tap) * CIN + cc * 64 + lk * 8;
        b0[n] = *(const s16x8*)wp;
        b1[n] = *(const s16x8*)(wp + 32);
      }
      #pragma unroll
      for (int mr = 0; mr < 4; ++mr) {
        const int pos = (wm + dy) * 66 + mr * 16 + lr + dx;
        s16x8 a0 = *(const s16x8*)(As + ((pos << 3) + (lk ^ (pos & 7))) * 8);
        s16x8 a1 = *(const s16x8*)(As + ((pos << 3) + ((4 + lk) ^ (pos & 7))) * 8);
        #pragma unroll
        for (int n = 0; n < 2; ++n) {
          acc[mr][n] = __builtin_amdgcn_mfma_f32_16x16x32_bf16(a0, b0[n], acc[mr][n], 0, 0, 0);
          acc[mr][n] = __builtin_amdgcn_mfma_f32_16x16x32_bf16(a1, b1[n], acc[mr][n], 0, 0, 0);
        }
      }
    }
  }
  __syncthreads();
  #pragma unroll
  for (int mr = 0; mr < 4; ++mr)
    #pragma unroll
    for (int n = 0; n < 2; ++n) {
      const int oc = wn * 32 + n * 16 + lr;
      const float bs = bias[ocb + oc];
      #pragma unroll
      for (int r = 0; r < 4; ++r)
        sm[(wm * 64 + mr * 16 + lk * 4 + r) * 65 + oc] =
            fmaxf(acc[mr][n][r] + bs, 0.f);
    }
  __syncthreads();
  if (POOL) {
    const int Wo = W >> 1;
    #pragma unroll
    for (int i = 0; i < 4; ++i) {
      int e = t + i * 256;
      int op = e & 31, xo = e >> 5;
      int oc0 = op * 2;
      float m0 = fmaxf(fmaxf(sm[(xo * 2) * 65 + oc0], sm[(xo * 2 + 1) * 65 + oc0]),
                       fmaxf(sm[(64 + xo * 2) * 65 + oc0], sm[(64 + xo * 2 + 1) * 65 + oc0]));
      float m1 = fmaxf(fmaxf(sm[(xo * 2) * 65 + oc0 + 1], sm[(xo * 2 + 1) * 65 + oc0 + 1]),
                       fmaxf(sm[(64 + xo * 2) * 65 + oc0 + 1], sm[(64 + xo * 2 + 1) * 65 + oc0 + 1]));
      size_t pos = (size_t)yp * Wo + (x0 >> 1) + xo;
      ((uint*)outB)[pos * (Cout >> 1) + ((ocb >> 1) + op)] =
          (uint)f2bf(m0) | ((uint)f2bf(m1) << 16);
    }
  } else {
    #pragma unroll
    for (int i = 0; i < 32; ++i) {
      int e = t + i * 256;
      int oc = e >> 7, sp = e & 127;
      outF[((size_t)(ocb + oc) * H + y0 + (sp >> 6)) * W + x0 + (sp & 63)] =
          sm[sp * 65 + oc];
    }
    if (WB16) {
      #pragma unroll
      for (int i = 0; i < 16; ++i) {
        int e = t + i * 256;
        int op = e & 31, sp = e >> 5;
        int oc0 = op * 2;
        float v0 = sm[sp * 65 + oc0], v1 = sm[sp * 65 + oc0 + 1];
        size_t pos = ((size_t)(y0 + (sp >> 6))) * W + x0 + (sp & 63);
        ((uint*)outB)[pos * (Cout >> 1) + ((ocb >> 1) + op)] =
            (uint)f2bf(v0) | ((uint)f2bf(v1) << 16);
      }
    }
  }
}

// ---------------------------------------------------------------------
extern "C" void kernel_launch(void* const* d_in, const int* in_sizes, int n_in,
                              void* d_out, int out_size, void* d_ws, size_t ws_size,
                              hipStream_t stream) {
  const float* df1 = (const float*)d_in[0];
  const float* df2 = (const float*)d_in[1];
  const float* img = (const float*)d_in[2];
  const float* w11 = (const float*)d_in[3];
  const float* b11 = (const float*)d_in[4];
  const float* w12 = (const float*)d_in[5];
  const float* b12 = (const float*)d_in[6];
  const float* w21 = (const float*)d_in[7];
  const float* b21 = (const float*)d_in[8];
  const float* w22 = (const float*)d_in[9];
  const float* b22 = (const float*)d_in[10];
  const float* w31 = (const float*)d_in[11];
  const float* b31 = (const float*)d_in[12];
  float* out = (float*)d_out;

  // ---- d_ws: [0,1.2MB) idxf + bf16 weights; [4MiB, +268MB) P4 planes /
  // VGG bf16 activations (overlay P4 after corr).
  int* idxf = (int*)d_ws;
  ushort* w12b = (ushort*)(idxf + 15376);
  ushort* w21b = w12b + 36864;
  ushort* w22b = w21b + 73728;
  ushort* w31b = w22b + 147456;
  float* P4 = (float*)((char*)d_ws + (size_t)(4 << 20));
  ushort* a11s = (ushort*)P4;
  ushort* p1bs = a11s + 16777216;
  ushort* a21s = p1bs + 4194304;
  ushort* p2bs = a21s + 8388608;

  // ---- d_out overlays (dead before real outputs land)
  ushort* n1b = (ushort*)(out + R21_OFF);
  ushort* n2b = n1b + 8388608;
  float* pv = out + OFF1_OFF;
  int*   pi = (int*)(out + OFF1_OFF + 953312);

  k_normalize<<<dim3(64, 4, 2), 256, 0, stream>>>(df1, df2, n1b, n2b);
  k_wprep_all<<<2160, 256, 0, stream>>>(w12, w21, w22, w31, w12b, w21b, w22b, w31b);

  k_pgemm_mfma<<<dim3(32, 32, 4), 256, 0, stream>>>(n1b, n2b, P4);
  k_corr<<<15376, 256, 0, stream>>>(P4, pv, pi);
  k_argmax<<<61, 256, 0, stream>>>(pv, pi, idxf);

  // ---- VGG chain, batched over samples (bf16 scratch overlays dead P4)
  k_conv11<<<dim3(256, 4), 256, 0, stream>>>(img, w11, b11, out + R11_OFF, a11s);
  k_mconv<64, true, false><<<dim3(512, 1, 4), 256, 0, stream>>>(
      a11s, w12b, b12, nullptr, p1bs, 256, 256, 64, 4194304, 0, 1048576);
  k_mconv<64, false, true><<<dim3(128, 2, 4), 256, 0, stream>>>(
      p1bs, w21b, b21, out + R21_OFF, a21s, 128, 128, 128, 1048576, 2097152, 2097152);
  k_mconv<128, true, false><<<dim3(128, 2, 4), 256, 0, stream>>>(
      a21s, w22b, b22, nullptr, p2bs, 128, 128, 128, 2097152, 0, 524288);
  k_mconv<128, false, false><<<dim3(32, 4, 4), 256, 0, stream>>>(
      p2bs, w31b, b31, out + R31_OFF, nullptr, 64, 64, 256, 524288, 1048576, 0);

  // ---- offset pyramids last (overwrite pv/pi region)
  k_flow_all<<<12096, 256, 0, stream>>>(idxf, out);
}

// Round 7
// 451.609 us; speedup vs baseline: 1.0677x; 1.0677x over previous
//
#include <hip/hip_runtime.h>

typedef __attribute__((ext_vector_type(4))) float f32x4;
typedef __attribute__((ext_vector_type(8))) short s16x8;

// ---------------- output layout (float element offsets) ----------------
#define OFF1_OFF 0
#define OFF2_OFF 4718592
#define OFF3_OFF 5898240
#define R11_OFF  6193152      // 4*64*256*256 f32
#define R21_OFF  22970368     // 4*128*128*128 f32 (n1b+n2b scratch pre-VGG)
#define R31_OFF  31358976     // 4*256*64*64 f32

__device__ __forceinline__ ushort f2bf(float x) {
  union { float f; uint u; } c; c.f = x;
  uint r = c.u + 0x7FFFu + ((c.u >> 16) & 1u);
  return (ushort)(r >> 16);
}
__device__ __forceinline__ float bfval(ushort h) {
  union { uint u; float f; } c; c.u = ((uint)h) << 16;
  return c.f;
}

// ---------------- per-pixel channel L2 normalize -> bf16 hi/lo pos-major
__global__ __launch_bounds__(256)
void k_normalize(const float* __restrict__ f1, const float* __restrict__ f2,
                 ushort* __restrict__ n1b, ushort* __restrict__ n2b) {
  __shared__ uint ldsu[64 * 256];
  float* red = (float*)ldsu;
  float* inv = (float*)ldsu + 256;
  const int t = threadIdx.x, x = t & 63, cg = t >> 6;
  const int h = blockIdx.x, b = blockIdx.y;
  const float* in = blockIdx.z ? f2 : f1;
  ushort* op = blockIdx.z ? n2b : n1b;
  const size_t base = (size_t)b * 256 * 4096 + (size_t)h * 64 + x;
  float vals[64];
  float s = 0.f;
  #pragma unroll
  for (int ci = 0; ci < 64; ++ci) {
    float v = in[base + (size_t)(cg * 64 + ci) * 4096];
    vals[ci] = v;
    s = fmaf(v, v, s);
  }
  red[t] = s;
  __syncthreads();
  if (t < 64) {
    float tot = red[t] + red[64 + t] + red[128 + t] + red[192 + t];
    inv[t] = 1.0f / fmaxf(sqrtf(tot), 1e-12f);
  }
  __syncthreads();
  const float iv = inv[x];
  __syncthreads();
  #pragma unroll
  for (int j = 0; j < 32; ++j) {
    float v0 = vals[2 * j] * iv, v1 = vals[2 * j + 1] * iv;
    ushort h0 = f2bf(v0), h1 = f2bf(v1);
    ushort l0 = f2bf(v0 - bfval(h0)), l1 = f2bf(v1 - bfval(h1));
    int cc = (cg << 1) + (j >> 4);
    int i = j & 15;
    int qh = cc * 32 + i, ql = cc * 32 + 16 + i;
    ldsu[x * 256 + (qh ^ (x & 31))] = (uint)h0 | ((uint)h1 << 16);
    ldsu[x * 256 + (ql ^ (x & 31))] = (uint)l0 | ((uint)l1 << 16);
  }
  __syncthreads();
  uint* og = (uint*)(op + ((size_t)b * 4096 + h * 64) * 512);
  #pragma unroll
  for (int it = 0; it < 64; ++it) {
    int idx = it * 256 + t;
    int p = idx >> 8, q = idx & 255;
    og[idx] = ldsu[p * 256 + (q ^ (p & 31))];
  }
}

// ---------------- pixel-correlation GEMM (MFMA bf16x3): P = A^T B -----
// batched z=4; P written PLANE-MAJOR: P[(uy*64+vy)*4096 + ux*64 + vx].
// (R5-proven version: 16x16 frags, conflict-free reads, reg-prefetch.)
__global__ __launch_bounds__(256)
void k_pgemm_mfma(const ushort* __restrict__ Ab0, const ushort* __restrict__ Bb0,
                  float* __restrict__ P0) {
  __shared__ __align__(16) ushort As[128 * 64];
  __shared__ __align__(16) ushort Bs[128 * 64];
  const int t = threadIdx.x;
  const int bz = blockIdx.z;
  const ushort* Ab = Ab0 + (size_t)bz * 2097152;
  const ushort* Bb = Bb0 + (size_t)bz * 2097152;
  float* P = P0 + (size_t)bz * 16777216;
  const int u0 = blockIdx.y * 128, v0 = blockIdx.x * 128;
  const int lane = t & 63, wv = t >> 6;
  const int wm = wv >> 1, wn = wv & 1;
  const int lr = lane & 15, lk = lane >> 4;
  int rowv[4], slotv[4];
  #pragma unroll
  for (int i = 0; i < 4; ++i) { int e = t + i * 256; rowv[i] = e >> 3; slotv[i] = e & 7; }
  s16x8 ra[4], rb[4];
  #pragma unroll
  for (int i = 0; i < 4; ++i) {
    ra[i] = *(const s16x8*)(Ab + ((size_t)(u0 + rowv[i])) * 512 + slotv[i] * 8);
    rb[i] = *(const s16x8*)(Bb + ((size_t)(v0 + rowv[i])) * 512 + slotv[i] * 8);
  }
  f32x4 acc[4][4];
  #pragma unroll
  for (int mt = 0; mt < 4; ++mt)
    #pragma unroll
    for (int nt = 0; nt < 4; ++nt) {
      f32x4 z = {0.f, 0.f, 0.f, 0.f};
      acc[mt][nt] = z;
    }

  #pragma unroll 1
  for (int cc = 0; cc < 8; ++cc) {
    __syncthreads();
    #pragma unroll
    for (int i = 0; i < 4; ++i) {
      *(s16x8*)(As + ((rowv[i] << 3) + (slotv[i] ^ (rowv[i] & 7))) * 8) = ra[i];
      *(s16x8*)(Bs + ((rowv[i] << 3) + (slotv[i] ^ (rowv[i] & 7))) * 8) = rb[i];
    }
    __syncthreads();
    if (cc < 7) {
      #pragma unroll
      for (int i = 0; i < 4; ++i) {
        ra[i] = *(const s16x8*)(Ab + ((size_t)(u0 + rowv[i])) * 512 + (cc + 1) * 64 + slotv[i] * 8);
        rb[i] = *(const s16x8*)(Bb + ((size_t)(v0 + rowv[i])) * 512 + (cc + 1) * 64 + slotv[i] * 8);
      }
    }
    s16x8 ah[4], al[4], bh[4], bl[4];
    #pragma unroll
    for (int mt = 0; mt < 4; ++mt) {
      int row = wm * 64 + mt * 16 + lr;
      ah[mt] = *(const s16x8*)(As + ((row << 3) + (lk ^ (row & 7))) * 8);
      al[mt] = *(const s16x8*)(As + ((row << 3) + ((4 + lk) ^ (row & 7))) * 8);
    }
    #pragma unroll
    for (int nt = 0; nt < 4; ++nt) {
      int row = wn * 64 + nt * 16 + lr;
      bh[nt] = *(const s16x8*)(Bs + ((row << 3) + (lk ^ (row & 7))) * 8);
      bl[nt] = *(const s16x8*)(Bs + ((row << 3) + ((4 + lk) ^ (row & 7))) * 8);
    }
    #pragma unroll
    for (int mt = 0; mt < 4; ++mt)
      #pragma unroll
      for (int nt = 0; nt < 4; ++nt) {
        acc[mt][nt] = __builtin_amdgcn_mfma_f32_16x16x32_bf16(al[mt], bh[nt], acc[mt][nt], 0, 0, 0);
        acc[mt][nt] = __builtin_amdgcn_mfma_f32_16x16x32_bf16(ah[mt], bl[nt], acc[mt][nt], 0, 0, 0);
        acc[mt][nt] = __builtin_amdgcn_mfma_f32_16x16x32_bf16(ah[mt], bh[nt], acc[mt][nt], 0, 0, 0);
      }
  }
  // plane-major epilogue: each wave owns one 64x64 plane
  const int plane = ((blockIdx.y * 2 + wm) << 6) + blockIdx.x * 2 + wn;
  float* Pp = P + (size_t)plane * 4096;
  #pragma unroll
  for (int mt = 0; mt < 4; ++mt)
    #pragma unroll
    for (int nt = 0; nt < 4; ++nt) {
      #pragma unroll
      for (int r = 0; r < 4; ++r)
        Pp[(mt * 16 + lk * 4 + r) * 64 + nt * 16 + lr] = acc[mt][nt][r];
    }
}

// ---------------- corr v2: separable 9-tap + partial argmax ----------
__global__ __launch_bounds__(256)
void k_corr(const float* __restrict__ P0, float* __restrict__ pv0,
            int* __restrict__ pi0) {
  __shared__ __align__(16) f32x4 Pl[3 * 1024];
  __shared__ float rv[256];
  __shared__ int   ri[256];
  const int t = threadIdx.x;
  const int orig = blockIdx.x;
  const int w = (orig & 7) * 1922 + (orig >> 3);
  const int bz = w / 3844;
  const int r2 = w % 3844;
  const int py = r2 / 62, qy = r2 % 62;
  const float* P = P0 + (size_t)bz * 16777216;
  float* pv = pv0 + (size_t)bz * 238328;
  int*   pi = pi0 + (size_t)bz * 238328;
  #pragma unroll
  for (int i = 0; i < 12; ++i) {
    int e = t + i * 256;
    int blk = e >> 10, rem = e & 1023;
    int px = rem >> 4, q4 = rem & 15;
    int pidx = (py + blk) * 64 + (qy + blk);
    f32x4 v = *(const f32x4*)(P + (size_t)pidx * 4096 + rem * 4);
    int slot = ((q4 + (px >> 4)) & 15) ^ (px & 15);
    Pl[blk * 1024 + px * 16 + slot] = v;
  }
  __syncthreads();
  const int px = t & 63, cg = t >> 6;
  #pragma unroll
  for (int j = 0; j < 4; ++j) {
    int c = cg * 4 + j;
    int slot = ((c + (px >> 4)) & 15) ^ (px & 15);
    int o = px * 16 + slot;
    Pl[o] = Pl[o] + Pl[1024 + o] + Pl[2048 + o];
  }
  __syncthreads();
  float bv = -3.4e38f; int bq = 0;
  if (px < 62) {
    const int q0 = cg * 16;
    const int nq = (cg < 3) ? 16 : 14;
    const int nch = (cg < 3) ? 5 : 4;
    float f[3][20];
    #pragma unroll
    for (int dj = 0; dj < 3; ++dj) {
      const int row = px + dj;
      const int rr = row >> 4, rm = row & 15;
      #pragma unroll
      for (int cc2 = 0; cc2 < 5; ++cc2) {
        if (cc2 < nch) {
          int c = cg * 4 + cc2;
          int slot = ((c + rr) & 15) ^ rm;
          f32x4 v = Pl[row * 16 + slot];
          f[dj][cc2 * 4 + 0] = v[0];
          f[dj][cc2 * 4 + 1] = v[1];
          f[dj][cc2 * 4 + 2] = v[2];
          f[dj][cc2 * 4 + 3] = v[3];
        }
      }
    }
    #pragma unroll
    for (int l = 0; l < 16; ++l) {
      if (l < nq) {
        float s = f[0][l] + f[1][l + 1] + f[2][l + 2];
        if (s > bv) { bv = s; bq = q0 + l; }
      }
    }
  }
  rv[t] = bv; ri[t] = bq;
  __syncthreads();
  if (t < 62) {
    float v = rv[t]; int q = ri[t];
    #pragma unroll
    for (int g = 1; g < 4; ++g) {
      float v2 = rv[g * 64 + t];
      if (v2 > v) { v = v2; q = ri[g * 64 + t]; }
    }
    const int n = py * 62 + t;
    pv[(size_t)n * 62 + qy] = v;
    pi[(size_t)n * 62 + qy] = qy * 62 + q;
  }
}

// ---------------- final argmax over the 62 qy partials ---------------
__global__ void k_argmax(const float* __restrict__ pv, const int* __restrict__ pi,
                         int* __restrict__ idxf) {
  int tid = blockIdx.x * 256 + threadIdx.x;
  if (tid >= 4 * 3844) return;
  const float* v = pv + (size_t)tid * 62;
  const int*  ii = pi + (size_t)tid * 62;
  float bv = v[0]; int bi = ii[0];
  for (int q = 1; q < 62; ++q) {
    float x = v[q];
    if (x > bv) { bv = x; bi = ii[q]; }
  }
  idxf[tid] = bi;
}

// ---------------- flow pyramid + 9 shifts (all 3 levels merged) ------
__global__ void k_flow_all(const int* __restrict__ idxf, float* __restrict__ out) {
  int gid = blockIdx.x * 256 + threadIdx.x;
  int Ho, lg, rel = gid;
  float* o;
  if (gid < 2359296)      { Ho = 256; lg = 2; o = out + OFF1_OFF; }
  else if (gid < 2949120) { Ho = 128; lg = 1; o = out + OFF2_OFF; rel -= 2359296; }
  else if (gid < 3096576) { Ho = 64;  lg = 0; o = out + OFF3_OFF; rel -= 2949120; }
  else return;
  const int x = rel % Ho;
  const int y = (rel / Ho) % Ho;
  const int s = (rel / (Ho * Ho)) % 9;
  const int b = rel / (Ho * Ho * 9);
  const int i = s / 3, j = s % 3;
  const int sc = 1 << lg;
  const int yy = y - i * sc, xx = x - j * sc;
  float fw = 0.f, fh = 0.f;
  if (yy >= 0 && xx >= 0) {
    const int r = yy >> lg, c = xx >> lg;
    if (r < 62 && c < 62) {
      const int id = idxf[b * 3844 + r * 62 + c];
      fw = (float)((id % 62 - c) * sc);
      fh = (float)((id / 62 - r) * sc);
    }
  }
  float2 ov = {fw, fh};
  *(float2*)(o + (size_t)rel * 2) = ov;
}

// ---------------- weight prep: f32 OIHW -> bf16 [oc][tap][ci] --------
__global__ void k_wprep_all(const float* __restrict__ w12, const float* __restrict__ w21,
                            const float* __restrict__ w22, const float* __restrict__ w31,
                            ushort* __restrict__ o12, ushort* __restrict__ o21,
                            ushort* __restrict__ o22, ushort* __restrict__ o31) {
  int gid = blockIdx.x * 256 + threadIdx.x;
  const float* w; ushort* o; int CIN, rel;
  if (gid < 36864)        { w = w12; o = o12; CIN = 64;  rel = gid; }
  else if (gid < 110592)  { w = w21; o = o21; CIN = 64;  rel = gid - 36864; }
  else if (gid < 258048)  { w = w22; o = o22; CIN = 128; rel = gid - 110592; }
  else if (gid < 552960)  { w = w31; o = o31; CIN = 128; rel = gid - 258048; }
  else return;
  int ci = rel % CIN;
  int r = rel / CIN;
  int tap = r % 9;
  int oc = r / 9;
  o[((size_t)oc * 9 + tap) * CIN + ci] = f2bf(w[((size_t)oc * CIN + ci) * 9 + tap]);
}

// ---------------- zero the 1-px borders of padded activation buffers --
// grid 387*256 = 99072 = 4 samples * 24768 s16x8 units
__global__ void k_zb(ushort* __restrict__ a11, ushort* __restrict__ p1,
                     ushort* __restrict__ a21, ushort* __restrict__ p2) {
  int gid = blockIdx.x * 256 + threadIdx.x;
  if (gid >= 99072) return;
  int b = gid / 24768, r = gid % 24768;
  ushort* p; int Hp, Wp, C8, u;
  size_t stride;
  if (r < 8224)       { p = a11; Hp = 258; Wp = 258; C8 = 8;  stride = 4260096; u = r; }
  else if (r < 12352) { p = p1;  Hp = 130; Wp = 130; C8 = 8;  stride = 1081600; u = r - 8224; }
  else if (r < 20608) { p = a21; Hp = 130; Wp = 130; C8 = 16; stride = 2163200; u = r - 12352; }
  else                { p = p2;  Hp = 66;  Wp = 66;  C8 = 16; stride = 557568;  u = r - 20608; }
  int pos = u / C8, j = u % C8;
  int row, col;
  if (pos < Wp)            { row = 0;      col = pos; }
  else if (pos < 2 * Wp)   { row = Hp - 1; col = pos - Wp; }
  else { int q = pos - 2 * Wp; row = 1 + (q >> 1); col = (q & 1) ? (Wp - 1) : 0; }
  s16x8 z = {0, 0, 0, 0, 0, 0, 0, 0};
  *(s16x8*)(p + (size_t)b * stride + (((size_t)row * Wp + col) * C8 + j) * 8) = z;
}

// ---------------- conv1_1 (batched y): 3->64, fused input norm --------
// outF: r11 f32 NCHW; outB: bf16 padded NHWC [258][258][64]
__global__ __launch_bounds__(256)
void k_conv11(const float* __restrict__ img0, const float* __restrict__ w,
              const float* __restrict__ bias, float* __restrict__ outF0,
              ushort* __restrict__ outB0) {
  __shared__ float wl[1728];
  __shared__ float bl[64];
  const int t = threadIdx.x;
  const int b = blockIdx.y;
  const float* img = img0 + (size_t)b * 3 * 65536;
  float* outF = outF0 + (size_t)b * 64 * 65536;
  ushort* outB = outB0 + (size_t)b * 4260096;
  for (int i = t; i < 1728; i += 256) wl[i] = w[i];
  if (t < 64) bl[t] = bias[t];
  __syncthreads();
  const int x = t, y = blockIdx.x;
  const float mean[3] = {0.485f, 0.456f, 0.406f};
  const float stdv[3] = {0.229f, 0.224f, 0.225f};
  float v[27];
  #pragma unroll
  for (int c = 0; c < 3; ++c)
    #pragma unroll
    for (int dy = 0; dy < 3; ++dy)
      #pragma unroll
      for (int dx = 0; dx < 3; ++dx) {
        int iy = y + dy - 1, ix = x + dx - 1;
        float val = 0.f;
        if (iy >= 0 && iy < 256 && ix >= 0 && ix < 256)
          val = (img[((size_t)c * 256 + iy) * 256 + ix] - mean[c]) / stdv[c];
        v[c * 9 + dy * 3 + dx] = val;
      }
  float ov[64];
  #pragma unroll 4
  for (int oc = 0; oc < 64; ++oc) {
    float a = bl[oc];
    #pragma unroll
    for (int k = 0; k < 27; ++k) a = fmaf(wl[oc * 27 + k], v[k], a);
    a = fmaxf(a, 0.f);
    ov[oc] = a;
    outF[((size_t)oc * 256 + y) * 256 + x] = a;
  }
  uint* ob = (uint*)(outB + (((size_t)(y + 1) * 258 + (x + 1)) << 6));
  #pragma unroll
  for (int j = 0; j < 32; ++j)
    ob[j] = (uint)f2bf(ov[2 * j]) | ((uint)f2bf(ov[2 * j + 1]) << 16);
}

// ---------------- MFMA 3x3 conv, single-pass bf16, padded NHWC in -----
// in: padded [H+2][PW][CIN] bf16 (border=0); staging via global_load_lds
// (linear LDS dest, inverse-swizzled global source). wB: [oc][tap][CIN].
template <int CIN, bool POOL, bool WB16>
__global__ __launch_bounds__(256)
void k_mconv(const ushort* __restrict__ inb, const ushort* __restrict__ wB,
             const float* __restrict__ bias, float* __restrict__ outF,
             ushort* __restrict__ outB, int H, int W, int Cout,
             int inStride, int fStride, int bStride, int PW, int POut) {
  __shared__ __align__(16) char lds_raw[33792];
  ushort* As = (ushort*)lds_raw;
  float*  sm = (float*)lds_raw;
  const int t = threadIdx.x;
  const int bz = blockIdx.z;
  inb += (size_t)bz * inStride;
  outF += (size_t)bz * fStride;
  outB += (size_t)bz * bStride;
  const int xtiles = W >> 6;
  const int xt = blockIdx.x % xtiles;
  const int yp = blockIdx.x / xtiles;
  const int x0 = xt << 6, y0 = yp << 1;
  const int ocb = blockIdx.y << 6;
  const int lane = t & 63, wv = t >> 6;
  const int wm = wv >> 1, wn = wv & 1;
  const int lr = lane & 15, lk = lane >> 4;
  constexpr int NC2 = CIN / 64;

  f32x4 acc[4][2];
  #pragma unroll
  for (int mr = 0; mr < 4; ++mr)
    #pragma unroll
    for (int n = 0; n < 2; ++n) {
      f32x4 z = {0.f, 0.f, 0.f, 0.f};
      acc[mr][n] = z;
    }

  #pragma unroll 1
  for (int cc = 0; cc < NC2; ++cc) {
    __syncthreads();
    // async stage: 2112 units of 16B; unit u -> LDS linear u*16B, global
    // channel-group gs = (u&7) ^ (pos&7) (same involution the reads use)
    #pragma unroll
    for (int i = 0; i < 9; ++i) {
      int e = t + i * 256;
      if (e < 2112) {
        int pos = e >> 3;
        int gs = (e & 7) ^ (pos & 7);
        int hy = pos / 66, hx = pos - hy * 66;
        __builtin_amdgcn_global_load_lds(
            (const __attribute__((address_space(1))) void*)(
                inb + ((size_t)(y0 + hy) * PW + x0 + hx) * CIN + cc * 64 + gs * 8),
            (__attribute__((address_space(3))) void*)(As + (size_t)e * 8), 16, 0, 0);
      }
    }
    __syncthreads();
    #pragma unroll 3
    for (int tap = 0; tap < 9; ++tap) {
      const int dy = tap / 3, dx = tap % 3;
      s16x8 b0[2], b1[2];
      #pragma unroll
      for (int n = 0; n < 2; ++n) {
        const ushort* wp =
            wB + ((size_t)(ocb + wn * 32 + n * 16 + lr) * 9 + tap) * CIN + cc * 64 + lk * 8;
        b0[n] = *(const s16x8*)wp;
        b1[n] = *(const s16x8*)(wp + 32);
      }
      #pragma unroll
      for (int mr = 0; mr < 4; ++mr) {
        const int pos = (wm + dy) * 66 + mr * 16 + lr + dx;
        s16x8 a0 = *(const s16x8*)(As + ((pos << 3) + (lk ^ (pos & 7))) * 8);
        s16x8 a1 = *(const s16x8*)(As + ((pos << 3) + ((4 + lk) ^ (pos & 7))) * 8);
        #pragma unroll
        for (int n = 0; n < 2; ++n) {
          acc[mr][n] = __builtin_amdgcn_mfma_f32_16x16x32_bf16(a0, b0[n], acc[mr][n], 0, 0, 0);
          acc[mr][n] = __builtin_amdgcn_mfma_f32_16x16x32_bf16(a1, b1[n], acc[mr][n], 0, 0, 0);
        }
      }
    }
  }
  __syncthreads();
  #pragma unroll
  for (int mr = 0; mr < 4; ++mr)
    #pragma unroll
    for (int n = 0; n < 2; ++n) {
      const int oc = wn * 32 + n * 16 + lr;
      const float bs = bias[ocb + oc];
      #pragma unroll
      for (int r = 0; r < 4; ++r)
        sm[(wm * 64 + mr * 16 + lk * 4 + r) * 65 + oc] =
            fmaxf(acc[mr][n][r] + bs, 0.f);
    }
  __syncthreads();
  if (POOL) {
    #pragma unroll
    for (int i = 0; i < 4; ++i) {
      int e = t + i * 256;
      int op = e & 31, xo = e >> 5;
      int oc0 = op * 2;
      float m0 = fmaxf(fmaxf(sm[(xo * 2) * 65 + oc0], sm[(xo * 2 + 1) * 65 + oc0]),
                       fmaxf(sm[(64 + xo * 2) * 65 + oc0], sm[(64 + xo * 2 + 1) * 65 + oc0]));
      float m1 = fmaxf(fmaxf(sm[(xo * 2) * 65 + oc0 + 1], sm[(xo * 2 + 1) * 65 + oc0 + 1]),
                       fmaxf(sm[(64 + xo * 2) * 65 + oc0 + 1], sm[(64 + xo * 2 + 1) * 65 + oc0 + 1]));
      size_t pos = (size_t)(yp + 1) * POut + (x0 >> 1) + xo + 1;
      ((uint*)outB)[pos * (Cout >> 1) + ((ocb >> 1) + op)] =
          (uint)f2bf(m0) | ((uint)f2bf(m1) << 16);
    }
  } else {
    #pragma unroll
    for (int i = 0; i < 32; ++i) {
      int e = t + i * 256;
      int oc = e >> 7, sp = e & 127;
      outF[((size_t)(ocb + oc) * H + y0 + (sp >> 6)) * W + x0 + (sp & 63)] =
          sm[sp * 65 + oc];
    }
    if (WB16) {
      #pragma unroll
      for (int i = 0; i < 16; ++i) {
        int e = t + i * 256;
        int op = e & 31, sp = e >> 5;
        int oc0 = op * 2;
        float v0 = sm[sp * 65 + oc0], v1 = sm[sp * 65 + oc0 + 1];
        size_t pos = (size_t)(y0 + (sp >> 6) + 1) * POut + x0 + (sp & 63) + 1;
        ((uint*)outB)[pos * (Cout >> 1) + ((ocb >> 1) + op)] =
            (uint)f2bf(v0) | ((uint)f2bf(v1) << 16);
      }
    }
  }
}

// ---------------------------------------------------------------------
extern "C" void kernel_launch(void* const* d_in, const int* in_sizes, int n_in,
                              void* d_out, int out_size, void* d_ws, size_t ws_size,
                              hipStream_t stream) {
  const float* df1 = (const float*)d_in[0];
  const float* df2 = (const float*)d_in[1];
  const float* img = (const float*)d_in[2];
  const float* w11 = (const float*)d_in[3];
  const float* b11 = (const float*)d_in[4];
  const float* w12 = (const float*)d_in[5];
  const float* b12 = (const float*)d_in[6];
  const float* w21 = (const float*)d_in[7];
  const float* b21 = (const float*)d_in[8];
  const float* w22 = (const float*)d_in[9];
  const float* b22 = (const float*)d_in[10];
  const float* w31 = (const float*)d_in[11];
  const float* b31 = (const float*)d_in[12];
  float* out = (float*)d_out;

  // ---- d_ws: [0,1.2MB) idxf + bf16 weights; [4MiB, +268MB) P4 planes /
  // padded VGG bf16 activations (overlay P4 after corr; borders zeroed).
  int* idxf = (int*)d_ws;
  ushort* w12b = (ushort*)(idxf + 15376);
  ushort* w21b = w12b + 36864;
  ushort* w22b = w21b + 73728;
  ushort* w31b = w22b + 147456;
  float* P4 = (float*)((char*)d_ws + (size_t)(4 << 20));
  ushort* a11s = (ushort*)P4;                 // 4 x [258][258][64]
  ushort* p1bs = a11s + 17040384;             // 4 x [130][130][64]
  ushort* a21s = p1bs + 4326400;              // 4 x [130][130][128]
  ushort* p2bs = a21s + 8652800;              // 4 x [66][66][128]

  // ---- d_out overlays (dead before real outputs land)
  ushort* n1b = (ushort*)(out + R21_OFF);
  ushort* n2b = n1b + 8388608;
  float* pv = out + OFF1_OFF;
  int*   pi = (int*)(out + OFF1_OFF + 953312);

  k_normalize<<<dim3(64, 4, 2), 256, 0, stream>>>(df1, df2, n1b, n2b);
  k_wprep_all<<<2160, 256, 0, stream>>>(w12, w21, w22, w31, w12b, w21b, w22b, w31b);

  k_pgemm_mfma<<<dim3(32, 32, 4), 256, 0, stream>>>(n1b, n2b, P4);
  k_corr<<<15376, 256, 0, stream>>>(P4, pv, pi);
  k_argmax<<<61, 256, 0, stream>>>(pv, pi, idxf);

  // ---- VGG chain (padded bf16 activations overlay dead P4)
  k_zb<<<387, 256, 0, stream>>>(a11s, p1bs, a21s, p2bs);
  k_conv11<<<dim3(256, 4), 256, 0, stream>>>(img, w11, b11, out + R11_OFF, a11s);
  k_mconv<64, true, false><<<dim3(512, 1, 4), 256, 0, stream>>>(
      a11s, w12b, b12, nullptr, p1bs, 256, 256, 64, 4260096, 0, 1081600, 258, 130);
  k_mconv<64, false, true><<<dim3(128, 2, 4), 256, 0, stream>>>(
      p1bs, w21b, b21, out + R21_OFF, a21s, 128, 128, 128, 1081600, 2097152, 2163200, 130, 130);
  k_mconv<128, true, false><<<dim3(128, 2, 4), 256, 0, stream>>>(
      a21s, w22b, b22, nullptr, p2bs, 128, 128, 128, 2163200, 0, 557568, 130, 66);
  k_mconv<128, false, false><<<dim3(32, 4, 4), 256, 0, stream>>>(
      p2bs, w31b, b31, out + R31_OFF, nullptr, 64, 64, 256, 557568, 1048576, 0, 66, 0);

  // ---- offset pyramids last (overwrite pv/pi region)
  k_flow_all<<<12096, 256, 0, stream>>>(idxf, out);
}

// Round 8
// 407.988 us; speedup vs baseline: 1.1818x; 1.1069x over previous
//
#include <hip/hip_runtime.h>

typedef __attribute__((ext_vector_type(4))) float f32x4;
typedef __attribute__((ext_vector_type(8))) short s16x8;

// ---------------- output layout (float element offsets) ----------------
#define OFF1_OFF 0
#define OFF2_OFF 4718592
#define OFF3_OFF 5898240
#define R11_OFF  6193152      // 4*64*256*256 f32
#define R21_OFF  22970368     // 4*128*128*128 f32 (n1b+n2b scratch pre-VGG)
#define R31_OFF  31358976     // 4*256*64*64 f32

__device__ __forceinline__ ushort f2bf(float x) {
  union { float f; uint u; } c; c.f = x;
  uint r = c.u + 0x7FFFu + ((c.u >> 16) & 1u);
  return (ushort)(r >> 16);
}
__device__ __forceinline__ float bfval(ushort h) {
  union { uint u; float f; } c; c.u = ((uint)h) << 16;
  return c.f;
}

// ---------------- per-pixel channel L2 normalize -> bf16 hi/lo pos-major
__global__ __launch_bounds__(256)
void k_normalize(const float* __restrict__ f1, const float* __restrict__ f2,
                 ushort* __restrict__ n1b, ushort* __restrict__ n2b) {
  __shared__ uint ldsu[64 * 256];
  float* red = (float*)ldsu;
  float* inv = (float*)ldsu + 256;
  const int t = threadIdx.x, x = t & 63, cg = t >> 6;
  const int h = blockIdx.x, b = blockIdx.y;
  const float* in = blockIdx.z ? f2 : f1;
  ushort* op = blockIdx.z ? n2b : n1b;
  const size_t base = (size_t)b * 256 * 4096 + (size_t)h * 64 + x;
  float vals[64];
  float s = 0.f;
  #pragma unroll
  for (int ci = 0; ci < 64; ++ci) {
    float v = in[base + (size_t)(cg * 64 + ci) * 4096];
    vals[ci] = v;
    s = fmaf(v, v, s);
  }
  red[t] = s;
  __syncthreads();
  if (t < 64) {
    float tot = red[t] + red[64 + t] + red[128 + t] + red[192 + t];
    inv[t] = 1.0f / fmaxf(sqrtf(tot), 1e-12f);
  }
  __syncthreads();
  const float iv = inv[x];
  __syncthreads();
  #pragma unroll
  for (int j = 0; j < 32; ++j) {
    float v0 = vals[2 * j] * iv, v1 = vals[2 * j + 1] * iv;
    ushort h0 = f2bf(v0), h1 = f2bf(v1);
    ushort l0 = f2bf(v0 - bfval(h0)), l1 = f2bf(v1 - bfval(h1));
    int cc = (cg << 1) + (j >> 4);
    int i = j & 15;
    int qh = cc * 32 + i, ql = cc * 32 + 16 + i;
    ldsu[x * 256 + (qh ^ (x & 31))] = (uint)h0 | ((uint)h1 << 16);
    ldsu[x * 256 + (ql ^ (x & 31))] = (uint)l0 | ((uint)l1 << 16);
  }
  __syncthreads();
  uint* og = (uint*)(op + ((size_t)b * 4096 + h * 64) * 512);
  #pragma unroll
  for (int it = 0; it < 64; ++it) {
    int idx = it * 256 + t;
    int p = idx >> 8, q = idx & 255;
    og[idx] = ldsu[p * 256 + (q ^ (p & 31))];
  }
}

// ---------------- pixel-correlation GEMM v4 (MFMA bf16x3) -------------
// batched z=4; P PLANE-MAJOR. T3+T4: glld dbuf, counted vmcnt(8) across
// barriers (drain only on last chunk); R5's conflict-free 16x16 reads.
__global__ __launch_bounds__(256)
void k_pgemm_mfma(const ushort* __restrict__ Ab0, const ushort* __restrict__ Bb0,
                  float* __restrict__ P0) {
  __shared__ __align__(16) ushort As[2][8192];
  __shared__ __align__(16) ushort Bs[2][8192];
  const int t = threadIdx.x;
  const int bz = blockIdx.z;
  const ushort* Ab = Ab0 + (size_t)bz * 2097152 + (size_t)blockIdx.y * 128 * 512;
  const ushort* Bb = Bb0 + (size_t)bz * 2097152 + (size_t)blockIdx.x * 128 * 512;
  float* P = P0 + (size_t)bz * 16777216;
  const int lane = t & 63, wv = t >> 6;
  const int wm = wv >> 1, wn = wv & 1;
  const int lr = lane & 15, lk = lane >> 4;

// LDS dest linear in unit u (wave-uniform base + lane*16); global source
// slot gs = (u&7)^(row&7) -> LDS content(row,s) = global(row, s^(row&7)),
// identical to R5's swizzled layout (reads unchanged, conflict-free).
#define STAGE(buf, cc)                                                          \
  do {                                                                          \
    _Pragma("unroll")                                                           \
    for (int j = 0; j < 4; ++j) {                                               \
      int u = t + j * 256;                                                      \
      int row = u >> 3;                                                         \
      int gs = (u & 7) ^ (row & 7);                                             \
      __builtin_amdgcn_global_load_lds(                                         \
          (const __attribute__((address_space(1))) void*)(Ab + (size_t)row * 512 + (cc) * 64 + gs * 8), \
          (__attribute__((address_space(3))) void*)(&As[buf][u * 8]), 16, 0, 0); \
      __builtin_amdgcn_global_load_lds(                                         \
          (const __attribute__((address_space(1))) void*)(Bb + (size_t)row * 512 + (cc) * 64 + gs * 8), \
          (__attribute__((address_space(3))) void*)(&Bs[buf][u * 8]), 16, 0, 0); \
    }                                                                           \
  } while (0)

  f32x4 acc[4][4];
  #pragma unroll
  for (int mt = 0; mt < 4; ++mt)
    #pragma unroll
    for (int nt = 0; nt < 4; ++nt) {
      f32x4 z = {0.f, 0.f, 0.f, 0.f};
      acc[mt][nt] = z;
    }

  STAGE(0, 0);
  STAGE(1, 1);

  #pragma unroll
  for (int cc = 0; cc < 8; ++cc) {
    const int cur = cc & 1;
    if (cc < 7) { asm volatile("s_waitcnt vmcnt(8)" ::: "memory"); }
    else        { asm volatile("s_waitcnt vmcnt(0)" ::: "memory"); }
    __builtin_amdgcn_s_barrier();
    __builtin_amdgcn_sched_barrier(0);
    const ushort* Asb = As[cur];
    const ushort* Bsb = Bs[cur];
    s16x8 ah[4], al[4], bh[4], bl[4];
    #pragma unroll
    for (int mt = 0; mt < 4; ++mt) {
      int row = wm * 64 + mt * 16 + lr;
      ah[mt] = *(const s16x8*)(Asb + ((row << 3) + (lk ^ (row & 7))) * 8);
      al[mt] = *(const s16x8*)(Asb + ((row << 3) + ((4 + lk) ^ (row & 7))) * 8);
    }
    #pragma unroll
    for (int nt = 0; nt < 4; ++nt) {
      int row = wn * 64 + nt * 16 + lr;
      bh[nt] = *(const s16x8*)(Bsb + ((row << 3) + (lk ^ (row & 7))) * 8);
      bl[nt] = *(const s16x8*)(Bsb + ((row << 3) + ((4 + lk) ^ (row & 7))) * 8);
    }
    #pragma unroll
    for (int mt = 0; mt < 4; ++mt)
      #pragma unroll
      for (int nt = 0; nt < 4; ++nt) {
        acc[mt][nt] = __builtin_amdgcn_mfma_f32_16x16x32_bf16(al[mt], bh[nt], acc[mt][nt], 0, 0, 0);
        acc[mt][nt] = __builtin_amdgcn_mfma_f32_16x16x32_bf16(ah[mt], bl[nt], acc[mt][nt], 0, 0, 0);
        acc[mt][nt] = __builtin_amdgcn_mfma_f32_16x16x32_bf16(ah[mt], bh[nt], acc[mt][nt], 0, 0, 0);
      }
    __builtin_amdgcn_sched_barrier(0);
    __builtin_amdgcn_s_barrier();
    if (cc < 6) STAGE(cur, cc + 2);
  }
#undef STAGE

  // plane-major epilogue: each wave owns one 64x64 plane
  const int plane = ((blockIdx.y * 2 + wm) << 6) + blockIdx.x * 2 + wn;
  float* Pp = P + (size_t)plane * 4096;
  #pragma unroll
  for (int mt = 0; mt < 4; ++mt)
    #pragma unroll
    for (int nt = 0; nt < 4; ++nt) {
      #pragma unroll
      for (int r = 0; r < 4; ++r)
        Pp[(mt * 16 + lk * 4 + r) * 64 + nt * 16 + lr] = acc[mt][nt][r];
    }
}

// ---------------- corr v2: separable 9-tap + partial argmax ----------
__global__ __launch_bounds__(256)
void k_corr(const float* __restrict__ P0, float* __restrict__ pv0,
            int* __restrict__ pi0) {
  __shared__ __align__(16) f32x4 Pl[3 * 1024];
  __shared__ float rv[256];
  __shared__ int   ri[256];
  const int t = threadIdx.x;
  const int orig = blockIdx.x;
  const int w = (orig & 7) * 1922 + (orig >> 3);
  const int bz = w / 3844;
  const int r2 = w % 3844;
  const int py = r2 / 62, qy = r2 % 62;
  const float* P = P0 + (size_t)bz * 16777216;
  float* pv = pv0 + (size_t)bz * 238328;
  int*   pi = pi0 + (size_t)bz * 238328;
  #pragma unroll
  for (int i = 0; i < 12; ++i) {
    int e = t + i * 256;
    int blk = e >> 10, rem = e & 1023;
    int px = rem >> 4, q4 = rem & 15;
    int pidx = (py + blk) * 64 + (qy + blk);
    f32x4 v = *(const f32x4*)(P + (size_t)pidx * 4096 + rem * 4);
    int slot = ((q4 + (px >> 4)) & 15) ^ (px & 15);
    Pl[blk * 1024 + px * 16 + slot] = v;
  }
  __syncthreads();
  const int px = t & 63, cg = t >> 6;
  #pragma unroll
  for (int j = 0; j < 4; ++j) {
    int c = cg * 4 + j;
    int slot = ((c + (px >> 4)) & 15) ^ (px & 15);
    int o = px * 16 + slot;
    Pl[o] = Pl[o] + Pl[1024 + o] + Pl[2048 + o];
  }
  __syncthreads();
  float bv = -3.4e38f; int bq = 0;
  if (px < 62) {
    const int q0 = cg * 16;
    const int nq = (cg < 3) ? 16 : 14;
    const int nch = (cg < 3) ? 5 : 4;
    float f[3][20];
    #pragma unroll
    for (int dj = 0; dj < 3; ++dj) {
      const int row = px + dj;
      const int rr = row >> 4, rm = row & 15;
      #pragma unroll
      for (int cc2 = 0; cc2 < 5; ++cc2) {
        if (cc2 < nch) {
          int c = cg * 4 + cc2;
          int slot = ((c + rr) & 15) ^ rm;
          f32x4 v = Pl[row * 16 + slot];
          f[dj][cc2 * 4 + 0] = v[0];
          f[dj][cc2 * 4 + 1] = v[1];
          f[dj][cc2 * 4 + 2] = v[2];
          f[dj][cc2 * 4 + 3] = v[3];
        }
      }
    }
    #pragma unroll
    for (int l = 0; l < 16; ++l) {
      if (l < nq) {
        float s = f[0][l] + f[1][l + 1] + f[2][l + 2];
        if (s > bv) { bv = s; bq = q0 + l; }
      }
    }
  }
  rv[t] = bv; ri[t] = bq;
  __syncthreads();
  if (t < 62) {
    float v = rv[t]; int q = ri[t];
    #pragma unroll
    for (int g = 1; g < 4; ++g) {
      float v2 = rv[g * 64 + t];
      if (v2 > v) { v = v2; q = ri[g * 64 + t]; }
    }
    const int n = py * 62 + t;
    pv[(size_t)n * 62 + qy] = v;
    pi[(size_t)n * 62 + qy] = qy * 62 + q;
  }
}

// ---------------- final argmax over the 62 qy partials ---------------
__global__ void k_argmax(const float* __restrict__ pv, const int* __restrict__ pi,
                         int* __restrict__ idxf) {
  int tid = blockIdx.x * 256 + threadIdx.x;
  if (tid >= 4 * 3844) return;
  const float* v = pv + (size_t)tid * 62;
  const int*  ii = pi + (size_t)tid * 62;
  float bv = v[0]; int bi = ii[0];
  for (int q = 1; q < 62; ++q) {
    float x = v[q];
    if (x > bv) { bv = x; bi = ii[q]; }
  }
  idxf[tid] = bi;
}

// ---------------- flow pyramid + 9 shifts (all 3 levels merged) ------
__global__ void k_flow_all(const int* __restrict__ idxf, float* __restrict__ out) {
  int gid = blockIdx.x * 256 + threadIdx.x;
  int Ho, lg, rel = gid;
  float* o;
  if (gid < 2359296)      { Ho = 256; lg = 2; o = out + OFF1_OFF; }
  else if (gid < 2949120) { Ho = 128; lg = 1; o = out + OFF2_OFF; rel -= 2359296; }
  else if (gid < 3096576) { Ho = 64;  lg = 0; o = out + OFF3_OFF; rel -= 2949120; }
  else return;
  const int x = rel % Ho;
  const int y = (rel / Ho) % Ho;
  const int s = (rel / (Ho * Ho)) % 9;
  const int b = rel / (Ho * Ho * 9);
  const int i = s / 3, j = s % 3;
  const int sc = 1 << lg;
  const int yy = y - i * sc, xx = x - j * sc;
  float fw = 0.f, fh = 0.f;
  if (yy >= 0 && xx >= 0) {
    const int r = yy >> lg, c = xx >> lg;
    if (r < 62 && c < 62) {
      const int id = idxf[b * 3844 + r * 62 + c];
      fw = (float)((id % 62 - c) * sc);
      fh = (float)((id / 62 - r) * sc);
    }
  }
  float2 ov = {fw, fh};
  *(float2*)(o + (size_t)rel * 2) = ov;
}

// ---------------- weight prep: f32 OIHW -> bf16 [oc][tap][ci] --------
__global__ void k_wprep_all(const float* __restrict__ w12, const float* __restrict__ w21,
                            const float* __restrict__ w22, const float* __restrict__ w31,
                            ushort* __restrict__ o12, ushort* __restrict__ o21,
                            ushort* __restrict__ o22, ushort* __restrict__ o31) {
  int gid = blockIdx.x * 256 + threadIdx.x;
  const float* w; ushort* o; int CIN, rel;
  if (gid < 36864)        { w = w12; o = o12; CIN = 64;  rel = gid; }
  else if (gid < 110592)  { w = w21; o = o21; CIN = 64;  rel = gid - 36864; }
  else if (gid < 258048)  { w = w22; o = o22; CIN = 128; rel = gid - 110592; }
  else if (gid < 552960)  { w = w31; o = o31; CIN = 128; rel = gid - 258048; }
  else return;
  int ci = rel % CIN;
  int r = rel / CIN;
  int tap = r % 9;
  int oc = r / 9;
  o[((size_t)oc * 9 + tap) * CIN + ci] = f2bf(w[((size_t)oc * CIN + ci) * 9 + tap]);
}

// ---------------- zero the 1-px borders of padded activation buffers --
__global__ void k_zb(ushort* __restrict__ a11, ushort* __restrict__ p1,
                     ushort* __restrict__ a21, ushort* __restrict__ p2) {
  int gid = blockIdx.x * 256 + threadIdx.x;
  if (gid >= 99072) return;
  int b = gid / 24768, r = gid % 24768;
  ushort* p; int Hp, Wp, C8, u;
  size_t stride;
  if (r < 8224)       { p = a11; Hp = 258; Wp = 258; C8 = 8;  stride = 4260096; u = r; }
  else if (r < 12352) { p = p1;  Hp = 130; Wp = 130; C8 = 8;  stride = 1081600; u = r - 8224; }
  else if (r < 20608) { p = a21; Hp = 130; Wp = 130; C8 = 16; stride = 2163200; u = r - 12352; }
  else                { p = p2;  Hp = 66;  Wp = 66;  C8 = 16; stride = 557568;  u = r - 20608; }
  int pos = u / C8, j = u % C8;
  int row, col;
  if (pos < Wp)            { row = 0;      col = pos; }
  else if (pos < 2 * Wp)   { row = Hp - 1; col = pos - Wp; }
  else { int q = pos - 2 * Wp; row = 1 + (q >> 1); col = (q & 1) ? (Wp - 1) : 0; }
  s16x8 z = {0, 0, 0, 0, 0, 0, 0, 0};
  *(s16x8*)(p + (size_t)b * stride + (((size_t)row * Wp + col) * C8 + j) * 8) = z;
}

// ---------------- conv1_1 v2: fused pack + coalesced padded-row write -
__global__ __launch_bounds__(256)
void k_conv11(const float* __restrict__ img0, const float* __restrict__ w,
              const float* __restrict__ bias, float* __restrict__ outF0,
              ushort* __restrict__ outB0) {
  __shared__ float wl[1728];
  __shared__ float bl[64];
  __shared__ uint ob[8192];               // 32 KB row staging (XOR-swizzled)
  const int t = threadIdx.x;
  const int b = blockIdx.y;
  const float* img = img0 + (size_t)b * 3 * 65536;
  float* outF = outF0 + (size_t)b * 64 * 65536;
  ushort* outB = outB0 + (size_t)b * 4260096;
  for (int i = t; i < 1728; i += 256) wl[i] = w[i];
  if (t < 64) bl[t] = bias[t];
  __syncthreads();
  const int x = t, y = blockIdx.x;
  const float mean[3] = {0.485f, 0.456f, 0.406f};
  const float stdv[3] = {0.229f, 0.224f, 0.225f};
  float v[27];
  #pragma unroll
  for (int c = 0; c < 3; ++c)
    #pragma unroll
    for (int dy = 0; dy < 3; ++dy)
      #pragma unroll
      for (int dx = 0; dx < 3; ++dx) {
        int iy = y + dy - 1, ix = x + dx - 1;
        float val = 0.f;
        if (iy >= 0 && iy < 256 && ix >= 0 && ix < 256)
          val = (img[((size_t)c * 256 + iy) * 256 + ix] - mean[c]) / stdv[c];
        v[c * 9 + dy * 3 + dx] = val;
      }
  const int xs = x & 31;
  #pragma unroll 4
  for (int op = 0; op < 32; ++op) {
    float a0 = bl[2 * op], a1 = bl[2 * op + 1];
    #pragma unroll
    for (int k = 0; k < 27; ++k) a0 = fmaf(wl[(2 * op) * 27 + k], v[k], a0);
    #pragma unroll
    for (int k = 0; k < 27; ++k) a1 = fmaf(wl[(2 * op + 1) * 27 + k], v[k], a1);
    a0 = fmaxf(a0, 0.f); a1 = fmaxf(a1, 0.f);
    outF[((size_t)(2 * op) * 256 + y) * 256 + x] = a0;
    outF[((size_t)(2 * op + 1) * 256 + y) * 256 + x] = a1;
    ob[x * 32 + (op ^ xs)] = (uint)f2bf(a0) | ((uint)f2bf(a1) << 16);
  }
  __syncthreads();
  // one contiguous 32 KB write: pos (y+1, 1..256) x 64 ushorts
  uint* og = (uint*)(outB + (((size_t)(y + 1) * 258 + 1) << 6));
  #pragma unroll
  for (int it = 0; it < 8; ++it) {
    int g4 = t + it * 256;
    int xx = g4 >> 3;
    int j0 = (g4 & 7) * 4;
    int xs2 = xx & 31;
    uint4 val;
    val.x = ob[xx * 32 + ((j0 + 0) ^ xs2)];
    val.y = ob[xx * 32 + ((j0 + 1) ^ xs2)];
    val.z = ob[xx * 32 + ((j0 + 2) ^ xs2)];
    val.w = ob[xx * 32 + ((j0 + 3) ^ xs2)];
    *(uint4*)(og + (size_t)g4 * 4) = val;
  }
}

// ---------------- MFMA 3x3 conv, single-pass bf16, padded NHWC in -----
template <int CIN, bool POOL, bool WB16>
__global__ __launch_bounds__(256)
void k_mconv(const ushort* __restrict__ inb, const ushort* __restrict__ wB,
             const float* __restrict__ bias, float* __restrict__ outF,
             ushort* __restrict__ outB, int H, int W, int Cout,
             int inStride, int fStride, int bStride, int PW, int POut) {
  __shared__ __align__(16) char lds_raw[33792];
  ushort* As = (ushort*)lds_raw;
  float*  sm = (float*)lds_raw;
  const int t = threadIdx.x;
  const int bz = blockIdx.z;
  inb += (size_t)bz * inStride;
  outF += (size_t)bz * fStride;
  outB += (size_t)bz * bStride;
  const int xtiles = W >> 6;
  const int xt = blockIdx.x % xtiles;
  const int yp = blockIdx.x / xtiles;
  const int x0 = xt << 6, y0 = yp << 1;
  const int ocb = blockIdx.y << 6;
  const int lane = t & 63, wv = t >> 6;
  const int wm = wv >> 1, wn = wv & 1;
  const int lr = lane & 15, lk = lane >> 4;
  constexpr int NC2 = CIN / 64;

  f32x4 acc[4][2];
  #pragma unroll
  for (int mr = 0; mr < 4; ++mr)
    #pragma unroll
    for (int n = 0; n < 2; ++n) {
      f32x4 z = {0.f, 0.f, 0.f, 0.f};
      acc[mr][n] = z;
    }

  #pragma unroll 1
  for (int cc = 0; cc < NC2; ++cc) {
    __syncthreads();
    #pragma unroll
    for (int i = 0; i < 9; ++i) {
      int e = t + i * 256;
      if (e < 2112) {
        int pos = e >> 3;
        int gs = (e & 7) ^ (pos & 7);
        int hy = pos / 66, hx = pos - hy * 66;
        __builtin_amdgcn_global_load_lds(
            (const __attribute__((address_space(1))) void*)(
                inb + ((size_t)(y0 + hy) * PW + x0 + hx) * CIN + cc * 64 + gs * 8),
            (__attribute__((address_space(3))) void*)(As + (size_t)e * 8), 16, 0, 0);
      }
    }
    __syncthreads();
    #pragma unroll 3
    for (int tap = 0; tap < 9; ++tap) {
      const int dy = tap / 3, dx = tap % 3;
      s16x8 b0[2], b1[2];
      #pragma unroll
      for (int n = 0; n < 2; ++n) {
        const ushort* wp =
            wB + ((size_t)(ocb + wn * 32 + n * 16 + lr) * 9 + tap) * CIN + cc * 64 + lk * 8;
        b0[n] = *(const s16x8*)wp;
        b1[n] = *(const s16x8*)(wp + 32);
      }
      #pragma unroll
      for (int mr = 0; mr < 4; ++mr) {
        const int pos = (wm + dy) * 66 + mr * 16 + lr + dx;
        s16x8 a0 = *(const s16x8*)(As + ((pos << 3) + (lk ^ (pos & 7))) * 8);
        s16x8 a1 = *(const s16x8*)(As + ((pos << 3) + ((4 + lk) ^ (pos & 7))) * 8);
        #pragma unroll
        for (int n = 0; n < 2; ++n) {
          acc[mr][n] = __builtin_amdgcn_mfma_f32_16x16x32_bf16(a0, b0[n], acc[mr][n], 0, 0, 0);
          acc[mr][n] = __builtin_amdgcn_mfma_f32_16x16x32_bf16(a1, b1[n], acc[mr][n], 0, 0, 0);
        }
      }
    }
  }
  __syncthreads();
  #pragma unroll
  for (int mr = 0; mr < 4; ++mr)
    #pragma unroll
    for (int n = 0; n < 2; ++n) {
      const int oc = wn * 32 + n * 16 + lr;
      const float bs = bias[ocb + oc];
      #pragma unroll
      for (int r = 0; r < 4; ++r)
        sm[(wm * 64 + mr * 16 + lk * 4 + r) * 65 + oc] =
            fmaxf(acc[mr][n][r] + bs, 0.f);
    }
  __syncthreads();
  if (POOL) {
    #pragma unroll
    for (int i = 0; i < 4; ++i) {
      int e = t + i * 256;
      int op = e & 31, xo = e >> 5;
      int oc0 = op * 2;
      float m0 = fmaxf(fmaxf(sm[(xo * 2) * 65 + oc0], sm[(xo * 2 + 1) * 65 + oc0]),
                       fmaxf(sm[(64 + xo * 2) * 65 + oc0], sm[(64 + xo * 2 + 1) * 65 + oc0]));
      float m1 = fmaxf(fmaxf(sm[(xo * 2) * 65 + oc0 + 1], sm[(xo * 2 + 1) * 65 + oc0 + 1]),
                       fmaxf(sm[(64 + xo * 2) * 65 + oc0 + 1], sm[(64 + xo * 2 + 1) * 65 + oc0 + 1]));
      size_t pos = (size_t)(yp + 1) * POut + (x0 >> 1) + xo + 1;
      ((uint*)outB)[pos * (Cout >> 1) + ((ocb >> 1) + op)] =
          (uint)f2bf(m0) | ((uint)f2bf(m1) << 16);
    }
  } else {
    #pragma unroll
    for (int i = 0; i < 32; ++i) {
      int e = t + i * 256;
      int oc = e >> 7, sp = e & 127;
      outF[((size_t)(ocb + oc) * H + y0 + (sp >> 6)) * W + x0 + (sp & 63)] =
          sm[sp * 65 + oc];
    }
    if (WB16) {
      #pragma unroll
      for (int i = 0; i < 16; ++i) {
        int e = t + i * 256;
        int op = e & 31, sp = e >> 5;
        int oc0 = op * 2;
        float v0 = sm[sp * 65 + oc0], v1 = sm[sp * 65 + oc0 + 1];
        size_t pos = (size_t)(y0 + (sp >> 6) + 1) * POut + x0 + (sp & 63) + 1;
        ((uint*)outB)[pos * (Cout >> 1) + ((ocb >> 1) + op)] =
            (uint)f2bf(v0) | ((uint)f2bf(v1) << 16);
      }
    }
  }
}

// ---------------------------------------------------------------------
extern "C" void kernel_launch(void* const* d_in, const int* in_sizes, int n_in,
                              void* d_out, int out_size, void* d_ws, size_t ws_size,
                              hipStream_t stream) {
  const float* df1 = (const float*)d_in[0];
  const float* df2 = (const float*)d_in[1];
  const float* img = (const float*)d_in[2];
  const float* w11 = (const float*)d_in[3];
  const float* b11 = (const float*)d_in[4];
  const float* w12 = (const float*)d_in[5];
  const float* b12 = (const float*)d_in[6];
  const float* w21 = (const float*)d_in[7];
  const float* b21 = (const float*)d_in[8];
  const float* w22 = (const float*)d_in[9];
  const float* b22 = (const float*)d_in[10];
  const float* w31 = (const float*)d_in[11];
  const float* b31 = (const float*)d_in[12];
  float* out = (float*)d_out;

  // ---- d_ws: [0,1.2MB) idxf + bf16 weights; [4MiB, +268MB) P4 planes /
  // padded VGG bf16 activations (overlay P4 after corr; borders zeroed).
  int* idxf = (int*)d_ws;
  ushort* w12b = (ushort*)(idxf + 15376);
  ushort* w21b = w12b + 36864;
  ushort* w22b = w21b + 73728;
  ushort* w31b = w22b + 147456;
  float* P4 = (float*)((char*)d_ws + (size_t)(4 << 20));
  ushort* a11s = (ushort*)P4;                 // 4 x [258][258][64]
  ushort* p1bs = a11s + 17040384;             // 4 x [130][130][64]
  ushort* a21s = p1bs + 4326400;              // 4 x [130][130][128]
  ushort* p2bs = a21s + 8652800;              // 4 x [66][66][128]

  // ---- d_out overlays (dead before real outputs land)
  ushort* n1b = (ushort*)(out + R21_OFF);
  ushort* n2b = n1b + 8388608;
  float* pv = out + OFF1_OFF;
  int*   pi = (int*)(out + OFF1_OFF + 953312);

  k_normalize<<<dim3(64, 4, 2), 256, 0, stream>>>(df1, df2, n1b, n2b);
  k_wprep_all<<<2160, 256, 0, stream>>>(w12, w21, w22, w31, w12b, w21b, w22b, w31b);

  k_pgemm_mfma<<<dim3(32, 32, 4), 256, 0, stream>>>(n1b, n2b, P4);
  k_corr<<<15376, 256, 0, stream>>>(P4, pv, pi);
  k_argmax<<<61, 256, 0, stream>>>(pv, pi, idxf);

  // ---- VGG chain (padded bf16 activations overlay dead P4)
  k_zb<<<387, 256, 0, stream>>>(a11s, p1bs, a21s, p2bs);
  k_conv11<<<dim3(256, 4), 256, 0, stream>>>(img, w11, b11, out + R11_OFF, a11s);
  k_mconv<64, true, false><<<dim3(512, 1, 4), 256, 0, stream>>>(
      a11s, w12b, b12, nullptr, p1bs, 256, 256, 64, 4260096, 0, 1081600, 258, 130);
  k_mconv<64, false, true><<<dim3(128, 2, 4), 256, 0, stream>>>(
      p1bs, w21b, b21, out + R21_OFF, a21s, 128, 128, 128, 1081600, 2097152, 2163200, 130, 130);
  k_mconv<128, true, false><<<dim3(128, 2, 4), 256, 0, stream>>>(
      a21s, w22b, b22, nullptr, p2bs, 128, 128, 128, 2163200, 0, 557568, 130, 66);
  k_mconv<128, false, false><<<dim3(32, 4, 4), 256, 0, stream>>>(
      p2bs, w31b, b31, out + R31_OFF, nullptr, 64, 64, 256, 557568, 1048576, 0, 66, 0);

  // ---- offset pyramids last (overwrite pv/pi region)
  k_flow_all<<<12096, 256, 0, stream>>>(idxf, out);
}